// Round 2
// baseline (119.306 us; speedup 1.0000x reference)
//
#include <hip/hip_runtime.h>

// Depthwise Gaussian blur K=121, replicate pad, separable, fp32. FUSED.
// R9 = R8 with the LOADG2 span-B offset bug fixed (+256 floats, not +1024:
// 32 groups * 8 floats = 256 floats; R8 applied the BYTE count to a float*).
// R8: (a) drop the 12-float group pad; 16B-unit XOR swizzle
//     (u ^= (u>>3)&7) on BOTH write and read sides. LDS 32.25->22.0 KB
//     -> 7 blocks/CU capacity vs grid's exact 6/CU -> whole grid
//     co-resident, kills the 2-of-6 half-occupancy tail (R7 ran 4
//     resident, then 2). phys(u+64)=phys(u)+64 and phys(2G+1)=phys(2G)^1
//     make the swizzled addressing CHEAPER than stride-12 (1 addr calc
//     per 4 ds_read_b128).
// (b) deferred normalization: wlds holds raw exp taps; per-wave butterfly
//     reduce for S; outputs scaled by 1/S^2 at the end. Removes 121
//     serial __expf+add from every thread.
// (c) halo fill vectorized to float4 (36 lanes instead of 144 scalar).

#define HH    512
#define WW    512
#define PLANE (512 * 512)
#define NIMG  24
#define ROWF  672                    // 168 16B-units/row; 21 octaves, swizzle-bijective

__device__ __forceinline__ void make_weights(const float* __restrict__ sigma,
                                             float* __restrict__ wlds, int tid) {
    if (tid < 128) {
        const float s = sigma[0] * 8.0f + 16.0f;
        const float inv2v = 1.0f / (2.0f * s * s);
        float g = 0.0f;
        if (tid < 121) {
            const float c = (float)tid - 60.0f;
            g = __expf(-c * c * inv2v);
        }
        wlds[tid] = g;               // UNNORMALIZED; taps 121..127 exactly 0
    }
}

// dword offset within an LDS row for padded column `col` (swizzled)
__device__ __forceinline__ int swz_off(int col) {
    const int u = col >> 2;
    return ((u ^ ((u >> 3) & 7)) << 2) + (col & 3);
}

// Vertical octet: prefetch next 8 window rows (float2, clamped), 8 taps x
// 8 output rows.
#define V_OCT(CUR, NXT, KO)                                               \
    { *(float4*)&wq[0] = *(const float4*)&wlds[(KO) * 8];                 \
      *(float4*)&wq[4] = *(const float4*)&wlds[(KO) * 8 + 4];             \
      _Pragma("unroll")                                                   \
      for (int ki = 0; ki < 8; ++ki) {                                    \
          int rr = r0 - 52 + (KO) * 8 + ki;                               \
          rr = rr < 0 ? 0 : (rr > HH - 1 ? HH - 1 : rr);                  \
          NXT[ki] = *(const float2*)&src[(size_t)rr * WW];                \
          const float wk = wq[ki];                                        \
          _Pragma("unroll")                                               \
          for (int j = 0; j < 8; ++j) {                                   \
              const int idx = ki + j;                                     \
              const float2 v = (idx < 8) ? CUR[idx] : NXT[idx - 8];       \
              vac[j].x += wk * v.x; vac[j].y += wk * v.y;                 \
          }                                                               \
      }                                                                   \
    }

// Load group G (span A) and G+32 (span B): one swizzled address serves all
// four b128s -- phys(2G+1)=phys(2G)^1 (same octave), phys(u+64)=phys(u)+64,
// so span B is a constant +64 units = +256 floats.
#define LOADG2(DA, DB, G)                                                 \
    { const int u_  = 2 * (G);                                            \
      const int o1_ = (u_ ^ ((u_ >> 3) & 7)) << 2;                        \
      const int o2_ = o1_ ^ 4;                                            \
      *(float4*)&DA[0] = *(const float4*)(bs + o1_);                      \
      *(float4*)&DA[4] = *(const float4*)(bs + o2_);                      \
      *(float4*)&DB[0] = *(const float4*)(bs + o1_ + 256);                \
      *(float4*)&DB[4] = *(const float4*)(bs + o2_ + 256); }

// One octet, TWO 8-col spans (A: groups L+.., B: groups L+32+..)
#define H_OCT2(A0, A1, A2, A3, B0, B1, B2, B3, KO)                        \
    { LOADG2(A3, B3, L + (KO) + 3)                                        \
      *(float4*)&wq[0] = *(const float4*)&wlds[(KO) * 8];                 \
      *(float4*)&wq[4] = *(const float4*)&wlds[(KO) * 8 + 4];             \
      _Pragma("unroll")                                                   \
      for (int ki = 0; ki < 8; ++ki) {                                    \
          const float wk = wq[ki];                                        \
          _Pragma("unroll")                                               \
          for (int j = 0; j < 8; ++j) {                                   \
              const int idx = ki + j;                                     \
              const float vA = (idx < 8) ? A0[idx]                        \
                             : (idx < 16) ? A1[idx - 8] : A2[idx - 16];   \
              const float vB = (idx < 8) ? B0[idx]                        \
                             : (idx < 16) ? B1[idx - 8] : B2[idx - 16];   \
              accA[j] += wk * vA;                                         \
              accB[j] += wk * vB;                                         \
          }                                                               \
      }                                                                   \
    }

__global__ __launch_bounds__(256, 6) void blur_fused(
        const float* __restrict__ x, const float* __restrict__ sigma,
        float* __restrict__ out) {
    __shared__ float sm[8 * ROWF];                   // 21504 B
    __shared__ float wlds[128];
    const int tid = threadIdx.x;

    // XCD swizzle: linear id -> contiguous 192-tile span per XCD (%8 rr).
    const int lid   = blockIdx.x + gridDim.x * blockIdx.y;   // 0..1535
    const int tile  = (lid & 7) * 192 + (lid >> 3);
    const int r0    = (tile & 63) * 8;               // output rows r0..r0+7
    const int plane = tile >> 6;

    const int c0 = tid * 2;                          // this thread's 2 cols
    const float* __restrict__ src = x + (size_t)plane * PLANE + c0;

    // ---- vertical: 8 rows x 2 cols per thread, global-streamed window ----
    float2 wa[8], wb[8], vac[8];
    float  wq[8];
    #pragma unroll
    for (int m = 0; m < 8; ++m) {                    // rows r0-60..r0-53
        int rr = r0 - 60 + m;
        rr = rr < 0 ? 0 : rr;
        wa[m] = *(const float2*)&src[(size_t)rr * WW];
    }
    make_weights(sigma, wlds, tid);                  // overlaps loads in flight
    #pragma unroll
    for (int j = 0; j < 8; ++j) vac[j] = make_float2(0.f, 0.f);
    __syncthreads();                                 // wlds ready

    // normalizer: S = sum of taps, once per wave (butterfly), scale at end
    const int lane = tid & 63;
    float s_sum = wlds[lane] + wlds[lane + 64];
    #pragma unroll
    for (int o = 32; o >= 1; o >>= 1) s_sum += __shfl_xor(s_sum, o);
    const float inv_s2 = 1.0f / (s_sum * s_sum);

    #pragma unroll 1
    for (int ko = 0; ko < 16; ko += 2) {
        V_OCT(wa, wb, ko)
        V_OCT(wb, wa, ko + 1)
    }

    // write intermediate at halo offset +60 (swizzled; float2 stays in-unit)
    {
        const int off = swz_off(c0 + 60);            // col even -> e in {0,2}
        #pragma unroll
        for (int j = 0; j < 8; ++j)
            *(float2*)&sm[j * ROWF + off] = vac[j];
    }
    __syncthreads();

    // ---- halo: cols 0..59 <- 60; 572..647 <- 571; zero 648..655 ----------
    if (tid < 36) {
        const int p = (tid < 15) ? tid * 4
                    : (tid < 34) ? 572 + (tid - 15) * 4
                                 : 648 + (tid - 34) * 4;
        const int u   = p >> 2;
        const int off = (u ^ ((u >> 3) & 7)) << 2;   // 16B-aligned
        const int soff = (tid < 15) ? swz_off(60) : swz_off(571);
        #pragma unroll
        for (int r8 = 0; r8 < 8; ++r8) {
            const float v = (tid < 34) ? sm[r8 * ROWF + soff] : 0.0f;
            *(float4*)&sm[r8 * ROWF + off] = make_float4(v, v, v, v);
        }
    }
    __syncthreads();

    // ---- horizontal: two 8-col spans per lane, rotating 4-octet windows --
    const int r = tid >> 5;                          // 0..7
    const int L = tid & 31;                          // span A cols 8L.., B +256
    const float* __restrict__ bs = sm + r * ROWF;

    float a0[8], a1[8], a2[8], a3[8];
    float b0[8], b1[8], b2[8], b3[8];
    float accA[8], accB[8];
    #pragma unroll
    for (int j = 0; j < 8; ++j) { accA[j] = 0.0f; accB[j] = 0.0f; }

    LOADG2(a0, b0, L)
    LOADG2(a1, b1, L + 1)
    LOADG2(a2, b2, L + 2)

    #pragma unroll 1
    for (int ko = 0; ko < 16; ko += 4) {
        H_OCT2(a0, a1, a2, a3, b0, b1, b2, b3, ko)
        H_OCT2(a1, a2, a3, a0, b1, b2, b3, b0, ko + 1)
        H_OCT2(a2, a3, a0, a1, b2, b3, b0, b1, ko + 2)
        H_OCT2(a3, a0, a1, a2, b3, b0, b1, b2, ko + 3)
    }

    float* __restrict__ dst = out + (size_t)plane * PLANE
                                  + (size_t)(r0 + r) * WW + L * 8;
    const float k2 = inv_s2;
    *(float4*)(dst)       = make_float4(accA[0] * k2, accA[1] * k2,
                                        accA[2] * k2, accA[3] * k2);
    *(float4*)(dst + 4)   = make_float4(accA[4] * k2, accA[5] * k2,
                                        accA[6] * k2, accA[7] * k2);
    *(float4*)(dst + 256) = make_float4(accB[0] * k2, accB[1] * k2,
                                        accB[2] * k2, accB[3] * k2);
    *(float4*)(dst + 260) = make_float4(accB[4] * k2, accB[5] * k2,
                                        accB[6] * k2, accB[7] * k2);
}

extern "C" void kernel_launch(void* const* d_in, const int* in_sizes, int n_in,
                              void* d_out, int out_size, void* d_ws, size_t ws_size,
                              hipStream_t stream) {
    const float* x     = (const float*)d_in[0];
    const float* sigma = (const float*)d_in[1];
    float* out = (float*)d_out;
    blur_fused<<<dim3(HH / 8, NIMG), dim3(256), 0, stream>>>(x, sigma, out);
}